// Round 1
// baseline (679.120 us; speedup 1.0000x reference)
//
#include <hip/hip_runtime.h>
#include <cstdint>
#include <cstddef>

#define T_STEPS 64
#define BATCH 512
#define IN_F 784
#define NKT 25          // k-tiles of 32 (784 padded to 800)
#define HID 2048
#define OUT_F 10

#define DEC_V 0.9f
#define DEC_I 0.8f
#define DT_V 0.1f
#define V_TH 0.5f

typedef __attribute__((ext_vector_type(8))) _Float16 f16x8;
typedef __attribute__((ext_vector_type(4))) float f32x4;

__device__ __forceinline__ void load_lds16h(const _Float16* g, _Float16* l) {
  __builtin_amdgcn_global_load_lds(
      (const __attribute__((address_space(1))) void*)g,
      (__attribute__((address_space(3))) void*)l, 16, 0, 0);
}

// ---------------------------------------------------------------------------
// Split fp32 [nrows,784] into f16 hi/lo in FRAGMENT-TILE order:
// tile (mt = row/16, kt = k/32) is 512 halves; within tile, lane l holds
// row (l&15), k-slice (l>>4)*8..+8 — exactly the MFMA A/B fragment, so the
// gemm can DMA tiles with global_load_lds (dest = base + lane*16B) or read
// fragments directly from global with one coalesced 16B/lane load.
// ---------------------------------------------------------------------------
__global__ __launch_bounds__(256)
void split_frag(const float* __restrict__ src, _Float16* __restrict__ hiT,
                _Float16* __restrict__ loT) {
  __shared__ float xr[16][804];              // stride 804: 16B-aligned, 2-way banks
  const int mt = blockIdx.x;
  for (int i = threadIdx.x; i < 16 * IN_F; i += 256) {
    const int r = i / IN_F, c = i - r * IN_F;
    xr[r][c] = src[(size_t)(mt * 16 + r) * IN_F + c];
  }
  for (int i = threadIdx.x; i < 16 * 16; i += 256)
    xr[i >> 4][IN_F + (i & 15)] = 0.0f;      // pad k 784..799
  __syncthreads();

  const int l = threadIdx.x & 63;
  const int g = threadIdx.x >> 6;
  const int r = l & 15, q = l >> 4;
  for (int kt = g; kt < NKT; kt += 4) {
    const float* s = &xr[r][kt * 32 + q * 8];
    f16x8 h, lo;
#pragma unroll
    for (int j = 0; j < 8; ++j) {
      const float v = s[j];
      const _Float16 hh = (_Float16)v;       // RTN
      h[j] = hh;
      lo[j] = (_Float16)(v - (float)hh);
    }
    const size_t off = ((size_t)mt * NKT + kt) * 512 + l * 8;
    *(f16x8*)&hiT[off] = h;
    *(f16x8*)&loT[off] = lo;
  }
}

// ---------------------------------------------------------------------------
// MFMA GEMM: C[m,n] = sum_k A[m,k]*W[n,k] via 3x f16-split products.
// Block tile 128(M) x 256(N), 4 waves, wave tile 64x128 = 4x8 16x16x32 tiles.
//
// R5 changes vs R4 (theory: exposed DMA latency per ktile, A refetched 8x):
//  - A staging double-buffered, ONE barrier per ktile. Stage for kt+1 is
//    issued right after the kt-1 end-barrier, so the compiler's vmcnt(0)
//    drain at the kt end-barrier lands after ~96 MFMAs of cover.
//  - W fragments read DIRECTLY from global (already fragment-ordered):
//    -8 DMAs and -16 LDS reads per wave per ktile; per-block W slice is
//    32KB/ktile -> L1/L2 resident. LDS use drops 48KB -> 32KB.
//  - Bijective XCD swizzle: each XCD owns a contiguous band of M (all N
//    strips) so the A panel is L2-reused instead of fetched 8x from HBM.
// ---------------------------------------------------------------------------
__global__ __launch_bounds__(256, 2)
void gemm_fc1(const _Float16* __restrict__ AhT, const _Float16* __restrict__ AlT,
              const _Float16* __restrict__ WhT, const _Float16* __restrict__ WlT,
              float* __restrict__ C) {
  __shared__ _Float16 __attribute__((aligned(16))) sAh[2][8 * 512];
  __shared__ _Float16 __attribute__((aligned(16))) sAl[2][8 * 512];

  const int tid = threadIdx.x;
  const int lane = tid & 63;
  const int wv = tid >> 6;

  // XCD-aware swizzle. nwg = 8 * (nrows/128) = 32*Tc, always % 8 == 0.
  const int nwg = gridDim.x * gridDim.y;
  const int bid = blockIdx.y * gridDim.x + blockIdx.x;   // hw dispatch order
  const int q = nwg >> 3;
  const int swz = (bid & 7) * q + (bid >> 3);
  const int bx = swz & 7;                                // gridDim.x == 8
  const int by = swz >> 3;

  const int bmT = by * 8;                    // A tile row base (m/16)
  const int bnT = bx * 16;                   // W tile row base (n/16)

  const int wrT = (wv >> 1) * 4;             // wave's A-tile offset (0/4)
  const int wcT = (wv & 1) * 8;              // wave's W-tile offset (0/8)
  const int col = lane & 15;
  const int quad = lane >> 4;

  f32x4 acc[4][8] = {};

  // prologue: stage kt=0 into buf 0
#pragma unroll
  for (int j = 0; j < 2; ++j) {
    const int t = wv * 2 + j;
    const size_t go = ((size_t)(bmT + t) * NKT + 0) * 512 + lane * 8;
    load_lds16h(AhT + go, &sAh[0][t * 512]);
    load_lds16h(AlT + go, &sAl[0][t * 512]);
  }
  __syncthreads();                           // vmcnt(0) drain: buf0 ready

  for (int kt = 0; kt < NKT; ++kt) {
    const int cur = kt & 1;
    // stage kt+1 into the other buffer (safe: previous end-barrier ordered
    // all reads of buf cur^1 before these writes)
    if (kt + 1 < NKT) {
#pragma unroll
      for (int j = 0; j < 2; ++j) {
        const int t = wv * 2 + j;
        const size_t go = ((size_t)(bmT + t) * NKT + (kt + 1)) * 512 + lane * 8;
        load_lds16h(AhT + go, &sAh[cur ^ 1][t * 512]);
        load_lds16h(AlT + go, &sAl[cur ^ 1][t * 512]);
      }
    }

    f16x8 fah[4], fal[4];
#pragma unroll
    for (int i = 0; i < 4; ++i) {
      fah[i] = *(const f16x8*)&sAh[cur][(wrT + i) * 512 + lane * 8];
      fal[i] = *(const f16x8*)&sAl[cur][(wrT + i) * 512 + lane * 8];
    }

    // W fragments directly from global: 1KB/wave coalesced, L1/L2-resident
    const size_t wbase = ((size_t)(bnT + wcT) * NKT + kt) * 512 + lane * 8;
#pragma unroll
    for (int ni = 0; ni < 8; ++ni) {
      const size_t wo = wbase + (size_t)ni * ((size_t)NKT * 512);
      const f16x8 fwh = *(const f16x8*)&WhT[wo];
      const f16x8 fwl = *(const f16x8*)&WlT[wo];
#pragma unroll
      for (int mi = 0; mi < 4; ++mi) {
        acc[mi][ni] = __builtin_amdgcn_mfma_f32_16x16x32_f16(fah[mi], fwh, acc[mi][ni], 0, 0, 0);
        acc[mi][ni] = __builtin_amdgcn_mfma_f32_16x16x32_f16(fah[mi], fwl, acc[mi][ni], 0, 0, 0);
        acc[mi][ni] = __builtin_amdgcn_mfma_f32_16x16x32_f16(fal[mi], fwh, acc[mi][ni], 0, 0, 0);
      }
    }
    // single barrier per ktile: vmcnt(0) drain (next-tile DMAs, covered by
    // the MFMAs above) + lgkmcnt (all waves done reading buf cur)
    __syncthreads();
  }

  // C/D layout: col = lane&15, row = quad*4 + reg (R3/R4-verified)
  const int rowb = by * 128 + (wv >> 1) * 64;
  const int colb = bx * 256 + (wv & 1) * 128;
#pragma unroll
  for (int mi = 0; mi < 4; ++mi)
#pragma unroll
    for (int ni = 0; ni < 8; ++ni)
#pragma unroll
      for (int r = 0; r < 4; ++r)
        C[(size_t)(rowb + mi * 16 + quad * 4 + r) * HID + colb + ni * 16 + col] =
            acc[mi][ni][r];
}

// ---------------------------------------------------------------------------
// Fused LIF scan + output projection partials (R4-verified, unchanged).
// ---------------------------------------------------------------------------
__global__ __launch_bounds__(256)
void lif_out(const float* __restrict__ cur, const float* __restrict__ wo,
             float* __restrict__ v1, float* __restrict__ i1,
             float* __restrict__ outP, int tc, int t0) {
  __shared__ _Float16 zL[T_STEPS][264];
  __shared__ _Float16 wT[16][264];

  const int tid = threadIdx.x;
  const int hc = blockIdx.x;
  const int b = blockIdx.y;
  const int hb = hc * 256;

  for (int i = tid; i < 16 * 256; i += 256) {
    const int n = i >> 8, k = i & 255;
    wT[n][k] = (n < OUT_F) ? (_Float16)wo[(size_t)n * HID + hb + k] : (_Float16)0.f;
  }

  const int sidx = b * HID + hb + tid;
  float v = v1[sidx];
  float ci = i1[sidx];
#pragma unroll 4
  for (int t = 0; t < tc; ++t) {
    const float c = cur[(size_t)t * (BATCH * HID) + sidx];
    const float vd = DEC_V * v + DT_V * ci;
    const float z = (vd > V_TH) ? 1.0f : 0.0f;
    v = (1.0f - z) * vd;
    ci = DEC_I * ci + c;
    zL[t][tid] = (_Float16)z;
  }
  v1[sidx] = v;
  i1[sidx] = ci;
  __syncthreads();

  const int wv = tid >> 6;
  const int lane = tid & 63;
  const int col = lane & 15;
  const int quad = lane >> 4;
  f32x4 acc = {};
  const _Float16* za = &zL[wv * 16 + col][0];
  const _Float16* wb = &wT[col][0];
#pragma unroll
  for (int ks = 0; ks < 8; ++ks) {
    f16x8 a = *(const f16x8*)(za + ks * 32 + quad * 8);
    f16x8 bb = *(const f16x8*)(wb + ks * 32 + quad * 8);
    acc = __builtin_amdgcn_mfma_f32_16x16x32_f16(a, bb, acc, 0, 0, 0);
  }
  if (col < OUT_F) {
#pragma unroll
    for (int r = 0; r < 4; ++r) {
      const int t = wv * 16 + quad * 4 + r;
      if (t < tc)
        outP[(((size_t)hc * T_STEPS + (t0 + t)) * BATCH + b) * OUT_F + col] = acc[r];
    }
  }
}

// ---------------------------------------------------------------------------
// LI readout: sum 8 chunk partials, scan, max. One thread per (b,o).
// ---------------------------------------------------------------------------
__global__ __launch_bounds__(256)
void li_scan(const float* __restrict__ outP, float* __restrict__ out) {
  const int idx = blockIdx.x * 256 + threadIdx.x;
  if (idx >= BATCH * OUT_F) return;
  float vo = 0.f, io = 0.f, vmax = 0.f;
  for (int t = 0; t < T_STEPS; ++t) {
    float oc = 0.f;
#pragma unroll
    for (int hc = 0; hc < 8; ++hc)
      oc += outP[((size_t)hc * T_STEPS + t) * (BATCH * OUT_F) + idx];
    const float von = DEC_V * vo + DT_V * io;
    io = DEC_I * io + oc;
    vo = von;
    vmax = fmaxf(vmax, von);
  }
  out[idx] = vmax;
}

__global__ void zero_state(float* __restrict__ p, int n) {
  int i = blockIdx.x * 256 + threadIdx.x;
  if (i < n) p[i] = 0.0f;
}

// ---------------------------------------------------------------------------
extern "C" void kernel_launch(void* const* d_in, const int* in_sizes, int n_in,
                              void* d_out, int out_size, void* d_ws, size_t ws_size,
                              hipStream_t stream) {
  const float* x  = (const float*)d_in[0];  // [T*B, 784]
  const float* w1 = (const float*)d_in[1];  // [2048, 784]
  const float* wo = (const float*)d_in[2];  // [10, 2048]
  float* out = (float*)d_out;               // [512, 10]

  const size_t BH = (size_t)BATCH * HID;
  const size_t WT_HALVES = (size_t)(HID / 16) * NKT * 512;   // per W array

  // fixed: v1 | i1 | outP[8][T*B*10] | WhT | WlT ; chunk: cur | AhT | AlT
  float* v1 = (float*)d_ws;
  float* i1 = v1 + BH;
  float* outP = i1 + BH;
  _Float16* WhT = (_Float16*)(outP + (size_t)8 * T_STEPS * BATCH * OUT_F);
  _Float16* WlT = WhT + WT_HALVES;
  char* chunk0 = (char*)(WlT + WT_HALVES);

  const size_t base_bytes = (size_t)(chunk0 - (char*)d_ws);
  // per step: cur f32 [512,2048] + AhT/AlT f16 [32 tiles][25][512]
  const size_t per_step = BH * 4 + (size_t)2 * 32 * NKT * 512 * 2;
  int Tc = T_STEPS;
  while (Tc > 1 && base_bytes + (size_t)Tc * per_step > ws_size) Tc >>= 1;

  float* cur = (float*)chunk0;
  _Float16* AhT = (_Float16*)(cur + (size_t)Tc * BH);
  _Float16* AlT = AhT + (size_t)Tc * 32 * NKT * 512;

  split_frag<<<HID / 16, 256, 0, stream>>>(w1, WhT, WlT);
  zero_state<<<(int)((2 * BH + 255) / 256), 256, 0, stream>>>(v1, (int)(2 * BH));

  for (int t0 = 0; t0 < T_STEPS; t0 += Tc) {
    const int tc = (T_STEPS - t0 < Tc) ? (T_STEPS - t0) : Tc;
    const int nrows = tc * BATCH;
    split_frag<<<nrows / 16, 256, 0, stream>>>(x + (size_t)t0 * BATCH * IN_F, AhT, AlT);
    dim3 grid(HID / 256, nrows / 128);
    gemm_fc1<<<grid, 256, 0, stream>>>(AhT, AlT, WhT, WlT, cur);
    dim3 lgrid(HID / 256, BATCH);
    lif_out<<<lgrid, 256, 0, stream>>>(cur, wo, v1, i1, outP, tc, t0);
  }
  li_scan<<<(BATCH * OUT_F + 255) / 256, 256, 0, stream>>>(outP, out);
}

// Round 2
// 636.848 us; speedup vs baseline: 1.0664x; 1.0664x over previous
//
#include <hip/hip_runtime.h>
#include <cstdint>
#include <cstddef>

#define T_STEPS 64
#define BATCH 512
#define IN_F 784
#define NKT 25          // k-tiles of 32 (784 padded to 800)
#define HID 2048
#define OUT_F 10

#define DEC_V 0.9f
#define DEC_I 0.8f
#define DT_V 0.1f
#define V_TH 0.5f

typedef __attribute__((ext_vector_type(8))) _Float16 f16x8;
typedef __attribute__((ext_vector_type(4))) float f32x4;

__device__ __forceinline__ void load_lds16h(const _Float16* g, _Float16* l) {
  __builtin_amdgcn_global_load_lds(
      (const __attribute__((address_space(1))) void*)g,
      (__attribute__((address_space(3))) void*)l, 16, 0, 0);
}

// ---------------------------------------------------------------------------
// Split fp32 [nrows,784] into f16 hi/lo in FRAGMENT-TILE order:
// tile (mt = row/16, kt = k/32) is 512 halves; within tile, lane l holds
// row (l&15), k-slice (l>>4)*8..+8 — exactly the MFMA A/B fragment, so the
// gemm can DMA tiles with global_load_lds (dest = base + lane*16B).
// ---------------------------------------------------------------------------
__global__ __launch_bounds__(256)
void split_frag(const float* __restrict__ src, _Float16* __restrict__ hiT,
                _Float16* __restrict__ loT) {
  __shared__ float xr[16][804];              // stride 804: 16B-aligned, 2-way banks
  const int mt = blockIdx.x;
  for (int i = threadIdx.x; i < 16 * IN_F; i += 256) {
    const int r = i / IN_F, c = i - r * IN_F;
    xr[r][c] = src[(size_t)(mt * 16 + r) * IN_F + c];
  }
  for (int i = threadIdx.x; i < 16 * 16; i += 256)
    xr[i >> 4][IN_F + (i & 15)] = 0.0f;      // pad k 784..799
  __syncthreads();

  const int l = threadIdx.x & 63;
  const int g = threadIdx.x >> 6;
  const int r = l & 15, q = l >> 4;
  for (int kt = g; kt < NKT; kt += 4) {
    const float* s = &xr[r][kt * 32 + q * 8];
    f16x8 h, lo;
#pragma unroll
    for (int j = 0; j < 8; ++j) {
      const float v = s[j];
      const _Float16 hh = (_Float16)v;       // RTN
      h[j] = hh;
      lo[j] = (_Float16)(v - (float)hh);
    }
    const size_t off = ((size_t)mt * NKT + kt) * 512 + l * 8;
    *(f16x8*)&hiT[off] = h;
    *(f16x8*)&loT[off] = lo;
  }
}

// ---------------------------------------------------------------------------
// MFMA GEMM: C[m,n] = sum_k A[m,k]*W[n,k] via 3x f16-split products.
//
// R6: 256(M) x 256(N) block tile, 512 threads (8 waves, 2x4), wave tile
// 128x64 = 8x4 tiles of 16x16x32. BOTH operands staged via global_load_lds,
// double-buffered, ONE barrier per ktile (T3-minimum 2-phase recipe):
//   stage(kt+1, buf^1) -> ds_read frags(buf) -> 96 MFMA -> __syncthreads()
// The end-barrier's vmcnt(0) drain lands after a full compute phase of
// cover; no direct global loads pollute the vmcnt queue (R5's mistake).
// LDS = 4 arrays x 2 bufs x 16KB = 128KB -> 1 block/CU, 2 waves/SIMD.
// XCD swizzle kept from R5 (FETCH 423->159MB, verified).
// ---------------------------------------------------------------------------
__global__ __launch_bounds__(512, 2)
void gemm_fc1(const _Float16* __restrict__ AhT, const _Float16* __restrict__ AlT,
              const _Float16* __restrict__ WhT, const _Float16* __restrict__ WlT,
              float* __restrict__ C) {
  __shared__ _Float16 __attribute__((aligned(16))) sAh[2][16 * 512];
  __shared__ _Float16 __attribute__((aligned(16))) sAl[2][16 * 512];
  __shared__ _Float16 __attribute__((aligned(16))) sWh[2][16 * 512];
  __shared__ _Float16 __attribute__((aligned(16))) sWl[2][16 * 512];

  const int tid = threadIdx.x;
  const int lane = tid & 63;
  const int wv = tid >> 6;                   // 0..7

  // Bijective XCD swizzle: nwg = 8 * (nrows/256), always % 8 == 0.
  const int nwg = gridDim.x * gridDim.y;
  const int bid = blockIdx.y * gridDim.x + blockIdx.x;   // hw dispatch order
  const int q = nwg >> 3;
  const int swz = (bid & 7) * q + (bid >> 3);
  const int bx = swz & 7;                                // gridDim.x == 8
  const int by = swz >> 3;

  const int bmT = by * 16;                   // A tile row base (m/16)
  const int bnT = bx * 16;                   // W tile row base (n/16)

  const int wr = wv >> 2;                    // 0..1: wave row (128 M each)
  const int wc = wv & 3;                     // 0..3: wave col (64 N each)
  const int col = lane & 15;
  const int quad = lane >> 4;

  f32x4 acc[8][4] = {};

  // Each wave DMAs 2 A-tiles + 2 W-tiles (hi+lo each) = 8 DMAs / ktile.
#define STAGE(KT, BUF)                                                       \
  do {                                                                       \
    _Pragma("unroll")                                                        \
    for (int j = 0; j < 2; ++j) {                                            \
      const int t = wv * 2 + j;                                              \
      const size_t ga = ((size_t)(bmT + t) * NKT + (KT)) * 512 + lane * 8;   \
      load_lds16h(AhT + ga, &sAh[BUF][t * 512]);                             \
      load_lds16h(AlT + ga, &sAl[BUF][t * 512]);                             \
      const size_t gw = ((size_t)(bnT + t) * NKT + (KT)) * 512 + lane * 8;   \
      load_lds16h(WhT + gw, &sWh[BUF][t * 512]);                             \
      load_lds16h(WlT + gw, &sWl[BUF][t * 512]);                             \
    }                                                                        \
  } while (0)

  STAGE(0, 0);
  __syncthreads();                           // buf0 ready

  for (int kt = 0; kt < NKT; ++kt) {
    const int cur = kt & 1;
    if (kt + 1 < NKT) STAGE(kt + 1, cur ^ 1);  // prefetch, drained at end-bar

    f16x8 fah[8], fal[8];
#pragma unroll
    for (int i = 0; i < 8; ++i) {
      fah[i] = *(const f16x8*)&sAh[cur][(wr * 8 + i) * 512 + lane * 8];
      fal[i] = *(const f16x8*)&sAl[cur][(wr * 8 + i) * 512 + lane * 8];
    }
#pragma unroll
    for (int nj = 0; nj < 4; ++nj) {
      const f16x8 fwh = *(const f16x8*)&sWh[cur][(wc * 4 + nj) * 512 + lane * 8];
      const f16x8 fwl = *(const f16x8*)&sWl[cur][(wc * 4 + nj) * 512 + lane * 8];
#pragma unroll
      for (int mi = 0; mi < 8; ++mi) {
        acc[mi][nj] = __builtin_amdgcn_mfma_f32_16x16x32_f16(fah[mi], fwh, acc[mi][nj], 0, 0, 0);
        acc[mi][nj] = __builtin_amdgcn_mfma_f32_16x16x32_f16(fah[mi], fwl, acc[mi][nj], 0, 0, 0);
        acc[mi][nj] = __builtin_amdgcn_mfma_f32_16x16x32_f16(fal[mi], fwh, acc[mi][nj], 0, 0, 0);
      }
    }
    __syncthreads();                         // drains prefetch (covered) + lgkm
  }
#undef STAGE

  // C/D layout: col = lane&15, row = quad*4 + reg (R3/R4-verified)
  const int rowb = by * 256 + wr * 128;
  const int colb = bx * 256 + wc * 64;
#pragma unroll
  for (int mi = 0; mi < 8; ++mi)
#pragma unroll
    for (int nj = 0; nj < 4; ++nj)
#pragma unroll
      for (int r = 0; r < 4; ++r)
        C[(size_t)(rowb + mi * 16 + quad * 4 + r) * HID + colb + nj * 16 + col] =
            acc[mi][nj][r];
}

// ---------------------------------------------------------------------------
// Fused LIF scan + output projection partials (R4-verified, unchanged).
// ---------------------------------------------------------------------------
__global__ __launch_bounds__(256)
void lif_out(const float* __restrict__ cur, const float* __restrict__ wo,
             float* __restrict__ v1, float* __restrict__ i1,
             float* __restrict__ outP, int tc, int t0) {
  __shared__ _Float16 zL[T_STEPS][264];
  __shared__ _Float16 wT[16][264];

  const int tid = threadIdx.x;
  const int hc = blockIdx.x;
  const int b = blockIdx.y;
  const int hb = hc * 256;

  for (int i = tid; i < 16 * 256; i += 256) {
    const int n = i >> 8, k = i & 255;
    wT[n][k] = (n < OUT_F) ? (_Float16)wo[(size_t)n * HID + hb + k] : (_Float16)0.f;
  }

  const int sidx = b * HID + hb + tid;
  float v = v1[sidx];
  float ci = i1[sidx];
#pragma unroll 4
  for (int t = 0; t < tc; ++t) {
    const float c = cur[(size_t)t * (BATCH * HID) + sidx];
    const float vd = DEC_V * v + DT_V * ci;
    const float z = (vd > V_TH) ? 1.0f : 0.0f;
    v = (1.0f - z) * vd;
    ci = DEC_I * ci + c;
    zL[t][tid] = (_Float16)z;
  }
  v1[sidx] = v;
  i1[sidx] = ci;
  __syncthreads();

  const int wv = tid >> 6;
  const int lane = tid & 63;
  const int col = lane & 15;
  const int quad = lane >> 4;
  f32x4 acc = {};
  const _Float16* za = &zL[wv * 16 + col][0];
  const _Float16* wb = &wT[col][0];
#pragma unroll
  for (int ks = 0; ks < 8; ++ks) {
    f16x8 a = *(const f16x8*)(za + ks * 32 + quad * 8);
    f16x8 bb = *(const f16x8*)(wb + ks * 32 + quad * 8);
    acc = __builtin_amdgcn_mfma_f32_16x16x32_f16(a, bb, acc, 0, 0, 0);
  }
  if (col < OUT_F) {
#pragma unroll
    for (int r = 0; r < 4; ++r) {
      const int t = wv * 16 + quad * 4 + r;
      if (t < tc)
        outP[(((size_t)hc * T_STEPS + (t0 + t)) * BATCH + b) * OUT_F + col] = acc[r];
    }
  }
}

// ---------------------------------------------------------------------------
// LI readout: sum 8 chunk partials, scan, max. One thread per (b,o).
// ---------------------------------------------------------------------------
__global__ __launch_bounds__(256)
void li_scan(const float* __restrict__ outP, float* __restrict__ out) {
  const int idx = blockIdx.x * 256 + threadIdx.x;
  if (idx >= BATCH * OUT_F) return;
  float vo = 0.f, io = 0.f, vmax = 0.f;
  for (int t = 0; t < T_STEPS; ++t) {
    float oc = 0.f;
#pragma unroll
    for (int hc = 0; hc < 8; ++hc)
      oc += outP[((size_t)hc * T_STEPS + t) * (BATCH * OUT_F) + idx];
    const float von = DEC_V * vo + DT_V * io;
    io = DEC_I * io + oc;
    vo = von;
    vmax = fmaxf(vmax, von);
  }
  out[idx] = vmax;
}

__global__ void zero_state(float* __restrict__ p, int n) {
  int i = blockIdx.x * 256 + threadIdx.x;
  if (i < n) p[i] = 0.0f;
}

// ---------------------------------------------------------------------------
extern "C" void kernel_launch(void* const* d_in, const int* in_sizes, int n_in,
                              void* d_out, int out_size, void* d_ws, size_t ws_size,
                              hipStream_t stream) {
  const float* x  = (const float*)d_in[0];  // [T*B, 784]
  const float* w1 = (const float*)d_in[1];  // [2048, 784]
  const float* wo = (const float*)d_in[2];  // [10, 2048]
  float* out = (float*)d_out;               // [512, 10]

  const size_t BH = (size_t)BATCH * HID;
  const size_t WT_HALVES = (size_t)(HID / 16) * NKT * 512;   // per W array

  // fixed: v1 | i1 | outP[8][T*B*10] | WhT | WlT ; chunk: cur | AhT | AlT
  float* v1 = (float*)d_ws;
  float* i1 = v1 + BH;
  float* outP = i1 + BH;
  _Float16* WhT = (_Float16*)(outP + (size_t)8 * T_STEPS * BATCH * OUT_F);
  _Float16* WlT = WhT + WT_HALVES;
  char* chunk0 = (char*)(WlT + WT_HALVES);

  const size_t base_bytes = (size_t)(chunk0 - (char*)d_ws);
  // per step: cur f32 [512,2048] + AhT/AlT f16 [32 tiles][25][512]
  const size_t per_step = BH * 4 + (size_t)2 * 32 * NKT * 512 * 2;
  int Tc = T_STEPS;
  while (Tc > 1 && base_bytes + (size_t)Tc * per_step > ws_size) Tc >>= 1;

  float* cur = (float*)chunk0;
  _Float16* AhT = (_Float16*)(cur + (size_t)Tc * BH);
  _Float16* AlT = AhT + (size_t)Tc * 32 * NKT * 512;

  split_frag<<<HID / 16, 256, 0, stream>>>(w1, WhT, WlT);
  zero_state<<<(int)((2 * BH + 255) / 256), 256, 0, stream>>>(v1, (int)(2 * BH));

  for (int t0 = 0; t0 < T_STEPS; t0 += Tc) {
    const int tc = (T_STEPS - t0 < Tc) ? (T_STEPS - t0) : Tc;
    const int nrows = tc * BATCH;
    split_frag<<<nrows / 16, 256, 0, stream>>>(x + (size_t)t0 * BATCH * IN_F, AhT, AlT);
    dim3 grid(HID / 256, nrows / 256);       // 256x256 block tile, 512 thr
    gemm_fc1<<<grid, 512, 0, stream>>>(AhT, AlT, WhT, WlT, cur);
    dim3 lgrid(HID / 256, BATCH);
    lif_out<<<lgrid, 256, 0, stream>>>(cur, wo, v1, i1, outP, tc, t0);
  }
  li_scan<<<(BATCH * OUT_F + 255) / 256, 256, 0, stream>>>(outP, out);
}

// Round 3
// 614.863 us; speedup vs baseline: 1.1045x; 1.0358x over previous
//
#include <hip/hip_runtime.h>
#include <cstdint>
#include <cstddef>

#define T_STEPS 64
#define BATCH 512
#define IN_F 784
#define NKT 25          // k-tiles of 32 (784 padded to 800)
#define HID 2048
#define OUT_F 10

#define DEC_V 0.9f
#define DEC_I 0.8f
#define DT_V 0.1f
#define V_TH 0.5f

typedef __attribute__((ext_vector_type(8))) _Float16 f16x8;
typedef __attribute__((ext_vector_type(4))) float f32x4;

__device__ __forceinline__ void load_lds16h(const _Float16* g, _Float16* l) {
  __builtin_amdgcn_global_load_lds(
      (const __attribute__((address_space(1))) void*)g,
      (__attribute__((address_space(3))) void*)l, 16, 0, 0);
}

// Counted waits (T4). "memory" clobber pins surrounding memory ops;
// sched_barrier(0) stops reg-only MFMAs from hoisting past the wait (rule 18).
#define VMCNT(N)                                                     \
  do {                                                               \
    asm volatile("s_waitcnt vmcnt(" #N ")" ::: "memory");            \
    __builtin_amdgcn_sched_barrier(0);                               \
  } while (0)
#define LGKM0                                                        \
  do {                                                               \
    asm volatile("s_waitcnt lgkmcnt(0)" ::: "memory");               \
    __builtin_amdgcn_sched_barrier(0);                               \
  } while (0)

// ---------------------------------------------------------------------------
// Split fp32 [nrows,784] into f16 hi/lo in FRAGMENT-TILE order:
// tile (mt = row/16, kt = k/32) is 512 halves; within tile, lane l holds
// row (l&15), k-slice (l>>4)*8..+8 — exactly the MFMA A/B fragment, so the
// gemm can DMA tiles with global_load_lds (dest = base + lane*16B).
// ---------------------------------------------------------------------------
__global__ __launch_bounds__(256)
void split_frag(const float* __restrict__ src, _Float16* __restrict__ hiT,
                _Float16* __restrict__ loT) {
  __shared__ float xr[16][804];              // stride 804: 16B-aligned, 2-way banks
  const int mt = blockIdx.x;
  for (int i = threadIdx.x; i < 16 * IN_F; i += 256) {
    const int r = i / IN_F, c = i - r * IN_F;
    xr[r][c] = src[(size_t)(mt * 16 + r) * IN_F + c];
  }
  for (int i = threadIdx.x; i < 16 * 16; i += 256)
    xr[i >> 4][IN_F + (i & 15)] = 0.0f;      // pad k 784..799
  __syncthreads();

  const int l = threadIdx.x & 63;
  const int g = threadIdx.x >> 6;
  const int r = l & 15, q = l >> 4;
  for (int kt = g; kt < NKT; kt += 4) {
    const float* s = &xr[r][kt * 32 + q * 8];
    f16x8 h, lo;
#pragma unroll
    for (int j = 0; j < 8; ++j) {
      const float v = s[j];
      const _Float16 hh = (_Float16)v;       // RTN
      h[j] = hh;
      lo[j] = (_Float16)(v - (float)hh);
    }
    const size_t off = ((size_t)mt * NKT + kt) * 512 + l * 8;
    *(f16x8*)&hiT[off] = h;
    *(f16x8*)&loT[off] = lo;
  }
}

// ---------------------------------------------------------------------------
// MFMA GEMM: C[m,n] = sum_k A[m,k]*W[n,k] via 3x f16-split products.
//
// R7: same geometry as R6 (256x256 tile, 8 waves 2x4, wave tile 128x64,
// dbuf LDS 128KB, XCD swizzle) but the sync structure is the T4
// counted-vmcnt schedule instead of drain-0 __syncthreads():
//   STAGE(kt+1, buf^1)            ; 8 DMAs/wave, left IN FLIGHT
//   s_waitcnt vmcnt(8)            ; retires only the PREVIOUS ktile's 8
//   s_barrier                     ; all waves' kt-DMAs now visible
//   ds_read frags(buf) + 96 MFMA  ; compiler-scheduled lgkm pipelining
//   s_waitcnt lgkmcnt(0); s_barrier  ; reads done before buf overwrite
// R6's __syncthreads() compiled to vmcnt(0) drains of the just-issued
// prefetch every ktile (m233's 2-phase stall) — that was the 322us.
// ---------------------------------------------------------------------------
__global__ __launch_bounds__(512, 2)
void gemm_fc1(const _Float16* __restrict__ AhT, const _Float16* __restrict__ AlT,
              const _Float16* __restrict__ WhT, const _Float16* __restrict__ WlT,
              float* __restrict__ C) {
  __shared__ _Float16 __attribute__((aligned(16))) sAh[2][16 * 512];
  __shared__ _Float16 __attribute__((aligned(16))) sAl[2][16 * 512];
  __shared__ _Float16 __attribute__((aligned(16))) sWh[2][16 * 512];
  __shared__ _Float16 __attribute__((aligned(16))) sWl[2][16 * 512];

  const int tid = threadIdx.x;
  const int lane = tid & 63;
  const int wv = tid >> 6;                   // 0..7

  // Bijective XCD swizzle: nwg = 8 * (nrows/256) * ... always % 8 == 0.
  const int nwg = gridDim.x * gridDim.y;
  const int bid = blockIdx.y * gridDim.x + blockIdx.x;   // hw dispatch order
  const int q = nwg >> 3;
  const int swz = (bid & 7) * q + (bid >> 3);
  const int bx = swz & 7;                                // gridDim.x == 8
  const int by = swz >> 3;

  const int bmT = by * 16;                   // A tile row base (m/16)
  const int bnT = bx * 16;                   // W tile row base (n/16)

  const int wr = wv >> 2;                    // 0..1: wave row (128 M each)
  const int wc = wv & 3;                     // 0..3: wave col (64 N each)
  const int col = lane & 15;
  const int quad = lane >> 4;

  f32x4 acc[8][4] = {};

  // Each wave DMAs 2 A-tiles + 2 W-tiles (hi+lo each) = 8 DMAs / ktile.
#define STAGE(KT, BUF)                                                       \
  do {                                                                       \
    _Pragma("unroll")                                                        \
    for (int j = 0; j < 2; ++j) {                                            \
      const int t = wv * 2 + j;                                              \
      const size_t ga = ((size_t)(bmT + t) * NKT + (KT)) * 512 + lane * 8;   \
      load_lds16h(AhT + ga, &sAh[BUF][t * 512]);                             \
      load_lds16h(AlT + ga, &sAl[BUF][t * 512]);                             \
      const size_t gw = ((size_t)(bnT + t) * NKT + (KT)) * 512 + lane * 8;   \
      load_lds16h(WhT + gw, &sWh[BUF][t * 512]);                             \
      load_lds16h(WlT + gw, &sWl[BUF][t * 512]);                             \
    }                                                                        \
  } while (0)

  STAGE(0, 0);                               // prologue: kt=0 into buf 0

  for (int kt = 0; kt < NKT; ++kt) {
    const int cur = kt & 1;
    if (kt + 1 < NKT) {
      STAGE(kt + 1, cur ^ 1);                // 8 new DMAs, stay in flight
      VMCNT(8);                              // retire previous ktile's 8
    } else {
      VMCNT(0);                              // last tile: drain its own 8
    }
    __builtin_amdgcn_s_barrier();            // buf[cur] visible to all waves

    f16x8 fah[8], fal[8];
#pragma unroll
    for (int i = 0; i < 8; ++i) {
      fah[i] = *(const f16x8*)&sAh[cur][(wr * 8 + i) * 512 + lane * 8];
      fal[i] = *(const f16x8*)&sAl[cur][(wr * 8 + i) * 512 + lane * 8];
    }
#pragma unroll
    for (int nj = 0; nj < 4; ++nj) {
      const f16x8 fwh = *(const f16x8*)&sWh[cur][(wc * 4 + nj) * 512 + lane * 8];
      const f16x8 fwl = *(const f16x8*)&sWl[cur][(wc * 4 + nj) * 512 + lane * 8];
#pragma unroll
      for (int mi = 0; mi < 8; ++mi) {
        acc[mi][nj] = __builtin_amdgcn_mfma_f32_16x16x32_f16(fah[mi], fwh, acc[mi][nj], 0, 0, 0);
        acc[mi][nj] = __builtin_amdgcn_mfma_f32_16x16x32_f16(fah[mi], fwl, acc[mi][nj], 0, 0, 0);
        acc[mi][nj] = __builtin_amdgcn_mfma_f32_16x16x32_f16(fal[mi], fwh, acc[mi][nj], 0, 0, 0);
      }
    }
    LGKM0;                                   // this wave's ds_reads consumed
    __builtin_amdgcn_s_barrier();            // all reads done -> buf reusable
  }
#undef STAGE

  // C/D layout: col = lane&15, row = quad*4 + reg (R3/R4-verified).
  // nj innermost: consecutive stores walk consecutive 64B of one line.
  const int rowb = by * 256 + wr * 128;
  const int colb = bx * 256 + wc * 64;
#pragma unroll
  for (int mi = 0; mi < 8; ++mi)
#pragma unroll
    for (int r = 0; r < 4; ++r) {
      const size_t rowo = (size_t)(rowb + mi * 16 + quad * 4 + r) * HID;
#pragma unroll
      for (int nj = 0; nj < 4; ++nj)
        C[rowo + colb + nj * 16 + col] = acc[mi][nj][r];
    }
}

// ---------------------------------------------------------------------------
// Fused LIF scan + output projection partials (R4-verified, unchanged).
// ---------------------------------------------------------------------------
__global__ __launch_bounds__(256)
void lif_out(const float* __restrict__ cur, const float* __restrict__ wo,
             float* __restrict__ v1, float* __restrict__ i1,
             float* __restrict__ outP, int tc, int t0) {
  __shared__ _Float16 zL[T_STEPS][264];
  __shared__ _Float16 wT[16][264];

  const int tid = threadIdx.x;
  const int hc = blockIdx.x;
  const int b = blockIdx.y;
  const int hb = hc * 256;

  for (int i = tid; i < 16 * 256; i += 256) {
    const int n = i >> 8, k = i & 255;
    wT[n][k] = (n < OUT_F) ? (_Float16)wo[(size_t)n * HID + hb + k] : (_Float16)0.f;
  }

  const int sidx = b * HID + hb + tid;
  float v = v1[sidx];
  float ci = i1[sidx];
#pragma unroll 4
  for (int t = 0; t < tc; ++t) {
    const float c = cur[(size_t)t * (BATCH * HID) + sidx];
    const float vd = DEC_V * v + DT_V * ci;
    const float z = (vd > V_TH) ? 1.0f : 0.0f;
    v = (1.0f - z) * vd;
    ci = DEC_I * ci + c;
    zL[t][tid] = (_Float16)z;
  }
  v1[sidx] = v;
  i1[sidx] = ci;
  __syncthreads();

  const int wv = tid >> 6;
  const int lane = tid & 63;
  const int col = lane & 15;
  const int quad = lane >> 4;
  f32x4 acc = {};
  const _Float16* za = &zL[wv * 16 + col][0];
  const _Float16* wb = &wT[col][0];
#pragma unroll
  for (int ks = 0; ks < 8; ++ks) {
    f16x8 a = *(const f16x8*)(za + ks * 32 + quad * 8);
    f16x8 bb = *(const f16x8*)(wb + ks * 32 + quad * 8);
    acc = __builtin_amdgcn_mfma_f32_16x16x32_f16(a, bb, acc, 0, 0, 0);
  }
  if (col < OUT_F) {
#pragma unroll
    for (int r = 0; r < 4; ++r) {
      const int t = wv * 16 + quad * 4 + r;
      if (t < tc)
        outP[(((size_t)hc * T_STEPS + (t0 + t)) * BATCH + b) * OUT_F + col] = acc[r];
    }
  }
}

// ---------------------------------------------------------------------------
// LI readout: sum 8 chunk partials, scan, max. One thread per (b,o).
// ---------------------------------------------------------------------------
__global__ __launch_bounds__(256)
void li_scan(const float* __restrict__ outP, float* __restrict__ out) {
  const int idx = blockIdx.x * 256 + threadIdx.x;
  if (idx >= BATCH * OUT_F) return;
  float vo = 0.f, io = 0.f, vmax = 0.f;
  for (int t = 0; t < T_STEPS; ++t) {
    float oc = 0.f;
#pragma unroll
    for (int hc = 0; hc < 8; ++hc)
      oc += outP[((size_t)hc * T_STEPS + t) * (BATCH * OUT_F) + idx];
    const float von = DEC_V * vo + DT_V * io;
    io = DEC_I * io + oc;
    vo = von;
    vmax = fmaxf(vmax, von);
  }
  out[idx] = vmax;
}

__global__ void zero_state(float* __restrict__ p, int n) {
  int i = blockIdx.x * 256 + threadIdx.x;
  if (i < n) p[i] = 0.0f;
}

// ---------------------------------------------------------------------------
extern "C" void kernel_launch(void* const* d_in, const int* in_sizes, int n_in,
                              void* d_out, int out_size, void* d_ws, size_t ws_size,
                              hipStream_t stream) {
  const float* x  = (const float*)d_in[0];  // [T*B, 784]
  const float* w1 = (const float*)d_in[1];  // [2048, 784]
  const float* wo = (const float*)d_in[2];  // [10, 2048]
  float* out = (float*)d_out;               // [512, 10]

  const size_t BH = (size_t)BATCH * HID;
  const size_t WT_HALVES = (size_t)(HID / 16) * NKT * 512;   // per W array

  // fixed: v1 | i1 | outP[8][T*B*10] | WhT | WlT ; chunk: cur | AhT | AlT
  float* v1 = (float*)d_ws;
  float* i1 = v1 + BH;
  float* outP = i1 + BH;
  _Float16* WhT = (_Float16*)(outP + (size_t)8 * T_STEPS * BATCH * OUT_F);
  _Float16* WlT = WhT + WT_HALVES;
  char* chunk0 = (char*)(WlT + WT_HALVES);

  const size_t base_bytes = (size_t)(chunk0 - (char*)d_ws);
  // per step: cur f32 [512,2048] + AhT/AlT f16 [32 tiles][25][512]
  const size_t per_step = BH * 4 + (size_t)2 * 32 * NKT * 512 * 2;
  int Tc = T_STEPS;
  while (Tc > 1 && base_bytes + (size_t)Tc * per_step > ws_size) Tc >>= 1;

  float* cur = (float*)chunk0;
  _Float16* AhT = (_Float16*)(cur + (size_t)Tc * BH);
  _Float16* AlT = AhT + (size_t)Tc * 32 * NKT * 512;

  split_frag<<<HID / 16, 256, 0, stream>>>(w1, WhT, WlT);
  zero_state<<<(int)((2 * BH + 255) / 256), 256, 0, stream>>>(v1, (int)(2 * BH));

  for (int t0 = 0; t0 < T_STEPS; t0 += Tc) {
    const int tc = (T_STEPS - t0 < Tc) ? (T_STEPS - t0) : Tc;
    const int nrows = tc * BATCH;
    split_frag<<<nrows / 16, 256, 0, stream>>>(x + (size_t)t0 * BATCH * IN_F, AhT, AlT);
    dim3 grid(HID / 256, nrows / 256);       // 256x256 block tile, 512 thr
    gemm_fc1<<<grid, 512, 0, stream>>>(AhT, AlT, WhT, WlT, cur);
    dim3 lgrid(HID / 256, BATCH);
    lif_out<<<lgrid, 256, 0, stream>>>(cur, wo, v1, i1, outP, tc, t0);
  }
  li_scan<<<(BATCH * OUT_F + 255) / 256, 256, 0, stream>>>(outP, out);
}

// Round 4
// 597.485 us; speedup vs baseline: 1.1366x; 1.0291x over previous
//
#include <hip/hip_runtime.h>
#include <cstdint>
#include <cstddef>

#define T_STEPS 64
#define BATCH 512
#define IN_F 784
#define NKT 25          // k-tiles of 32 (784 padded to 800)
#define HID 2048
#define OUT_F 10

#define DEC_V 0.9f
#define DEC_I 0.8f
#define DT_V 0.1f
#define V_TH 0.5f

typedef __attribute__((ext_vector_type(8))) _Float16 f16x8;
typedef __attribute__((ext_vector_type(4))) float f32x4;

__device__ __forceinline__ void load_lds16h(const _Float16* g, _Float16* l) {
  __builtin_amdgcn_global_load_lds(
      (const __attribute__((address_space(1))) void*)g,
      (__attribute__((address_space(3))) void*)l, 16, 0, 0);
}

// Counted waits (T4). "memory" clobber pins surrounding memory ops;
// sched_barrier(0) stops reg-only MFMAs from hoisting past the wait (rule 18).
#define VMCNT0                                                       \
  do {                                                               \
    asm volatile("s_waitcnt vmcnt(0)" ::: "memory");                 \
    __builtin_amdgcn_sched_barrier(0);                               \
  } while (0)
#define LGKM0                                                        \
  do {                                                               \
    asm volatile("s_waitcnt lgkmcnt(0)" ::: "memory");               \
    __builtin_amdgcn_sched_barrier(0);                               \
  } while (0)
#define BAR __builtin_amdgcn_s_barrier()
#define PRIO1 __builtin_amdgcn_s_setprio(1)
#define PRIO0 __builtin_amdgcn_s_setprio(0)

// ---------------------------------------------------------------------------
// Split fp32 [nrows,784] into f16 hi/lo in FRAGMENT-TILE order:
// tile (mt = row/16, kt = k/32) is 512 halves; within tile, lane l holds
// row (l&15), k-slice (l>>4)*8..+8 — exactly the MFMA A/B fragment, so the
// gemm can DMA tiles with global_load_lds (dest = base + lane*16B).
// ---------------------------------------------------------------------------
__global__ __launch_bounds__(256)
void split_frag(const float* __restrict__ src, _Float16* __restrict__ hiT,
                _Float16* __restrict__ loT) {
  __shared__ float xr[16][804];              // stride 804: 16B-aligned, 2-way banks
  const int mt = blockIdx.x;
  for (int i = threadIdx.x; i < 16 * IN_F; i += 256) {
    const int r = i / IN_F, c = i - r * IN_F;
    xr[r][c] = src[(size_t)(mt * 16 + r) * IN_F + c];
  }
  for (int i = threadIdx.x; i < 16 * 16; i += 256)
    xr[i >> 4][IN_F + (i & 15)] = 0.0f;      // pad k 784..799
  __syncthreads();

  const int l = threadIdx.x & 63;
  const int g = threadIdx.x >> 6;
  const int r = l & 15, q = l >> 4;
  for (int kt = g; kt < NKT; kt += 4) {
    const float* s = &xr[r][kt * 32 + q * 8];
    f16x8 h, lo;
#pragma unroll
    for (int j = 0; j < 8; ++j) {
      const float v = s[j];
      const _Float16 hh = (_Float16)v;       // RTN
      h[j] = hh;
      lo[j] = (_Float16)(v - (float)hh);
    }
    const size_t off = ((size_t)mt * NKT + kt) * 512 + l * 8;
    *(f16x8*)&hiT[off] = h;
    *(f16x8*)&loT[off] = lo;
  }
}

// ---------------------------------------------------------------------------
// MFMA GEMM: C[m,n] = sum_k A[m,k]*W[n,k] via 3x f16-split products.
//
// R8: 8-phase-style fine interleave (T3+T4+T5) on R7's geometry.
// 256x256 tile, 8 waves (2M x 4N), wave tile 128x64 = 8mi x 4nj tiles,
// dbuf LDS 128KB, XCD swizzle. Per ktile, 4 phases by C-quadrant:
//   P0: ds_read A[mi0-3](8) + W[nj0-1](4) | issue 4 A-DMAs(kt+1)
//       BAR; lgkm0; prio1; 24 MFMA (mi0-3 x nj0-1); prio0; BAR
//   P1: ds_read W[nj2-3](4) | issue 4 W-DMAs(kt+1)
//       BAR; lgkm0; prio1; 24 MFMA (mi0-3 x nj2-3); prio0; BAR
//   P2: ds_read A[mi4-7](8)
//       BAR; lgkm0; prio1; 24 MFMA (mi4-7 x nj0-1); vmcnt(0); prio0; BAR
//   P3: 24 MFMA (mi4-7 x nj2-3) — register-only, NO barriers: overlaps
//       kt+1 P0's ds_read + DMA issue.
// vmcnt(0) fires once per ktile, after ~2.5 phases of MFMA cover; only
// kt+1's 8 DMAs are outstanding there (T4: never drain mid-pipeline).
// Race ledger: buf[cur] reads >= 1 barrier after its vmcnt; buf overwrite
// >= 2 barriers after last read (prev-ktile P2 lgkm0+BAR); W-frags live
// P0->P3; A-frags reloaded in P2 after P1 consumed them (reg WAR).
// ---------------------------------------------------------------------------
__global__ __launch_bounds__(512, 2)
void gemm_fc1(const _Float16* __restrict__ AhT, const _Float16* __restrict__ AlT,
              const _Float16* __restrict__ WhT, const _Float16* __restrict__ WlT,
              float* __restrict__ C) {
  __shared__ _Float16 __attribute__((aligned(16))) sAh[2][16 * 512];
  __shared__ _Float16 __attribute__((aligned(16))) sAl[2][16 * 512];
  __shared__ _Float16 __attribute__((aligned(16))) sWh[2][16 * 512];
  __shared__ _Float16 __attribute__((aligned(16))) sWl[2][16 * 512];

  const int tid = threadIdx.x;
  const int lane = tid & 63;
  const int wv = tid >> 6;                   // 0..7

  // Bijective XCD swizzle: nwg = 8 * (nrows/256), always % 8 == 0.
  const int nwg = gridDim.x * gridDim.y;
  const int bid = blockIdx.y * gridDim.x + blockIdx.x;   // hw dispatch order
  const int q = nwg >> 3;
  const int swz = (bid & 7) * q + (bid >> 3);
  const int bx = swz & 7;                                // gridDim.x == 8
  const int by = swz >> 3;

  const int bmT = by * 16;                   // A tile row base (m/16)
  const int bnT = bx * 16;                   // W tile row base (n/16)

  const int wr = wv >> 2;                    // 0..1: wave row (128 M each)
  const int wc = wv & 3;                     // 0..3: wave col (64 N each)
  const int col = lane & 15;
  const int quad = lane >> 4;

  f32x4 acc[8][4] = {};
  f16x8 fah[4], fal[4];                      // current mi-half A frags
  f16x8 fwh[4], fwl[4];                      // all 4 nj W frags (live P0->P3)

#define STAGE_A(KT, BUF)                                                     \
  do {                                                                       \
    _Pragma("unroll")                                                        \
    for (int j = 0; j < 2; ++j) {                                            \
      const int t = wv * 2 + j;                                              \
      const size_t ga = ((size_t)(bmT + t) * NKT + (KT)) * 512 + lane * 8;   \
      load_lds16h(AhT + ga, &sAh[BUF][t * 512]);                             \
      load_lds16h(AlT + ga, &sAl[BUF][t * 512]);                             \
    }                                                                        \
  } while (0)

#define STAGE_W(KT, BUF)                                                     \
  do {                                                                       \
    _Pragma("unroll")                                                        \
    for (int j = 0; j < 2; ++j) {                                            \
      const int t = wv * 2 + j;                                              \
      const size_t gw = ((size_t)(bnT + t) * NKT + (KT)) * 512 + lane * 8;   \
      load_lds16h(WhT + gw, &sWh[BUF][t * 512]);                             \
      load_lds16h(WlT + gw, &sWl[BUF][t * 512]);                             \
    }                                                                        \
  } while (0)

#define DS_A(MH)                                                             \
  do {                                                                       \
    _Pragma("unroll")                                                        \
    for (int i = 0; i < 4; ++i) {                                            \
      fah[i] = *(const f16x8*)&sAh[cur][(wr * 8 + (MH) * 4 + i) * 512 + lane * 8]; \
      fal[i] = *(const f16x8*)&sAl[cur][(wr * 8 + (MH) * 4 + i) * 512 + lane * 8]; \
    }                                                                        \
  } while (0)

#define DS_W(NH)                                                             \
  do {                                                                       \
    _Pragma("unroll")                                                        \
    for (int j = 0; j < 2; ++j) {                                            \
      fwh[(NH) * 2 + j] = *(const f16x8*)&sWh[cur][(wc * 4 + (NH) * 2 + j) * 512 + lane * 8]; \
      fwl[(NH) * 2 + j] = *(const f16x8*)&sWl[cur][(wc * 4 + (NH) * 2 + j) * 512 + lane * 8]; \
    }                                                                        \
  } while (0)

#define MM(MH, NH)                                                           \
  do {                                                                       \
    _Pragma("unroll")                                                        \
    for (int j = 0; j < 2; ++j)                                              \
      _Pragma("unroll")                                                      \
      for (int i = 0; i < 4; ++i) {                                          \
        acc[(MH) * 4 + i][(NH) * 2 + j] = __builtin_amdgcn_mfma_f32_16x16x32_f16( \
            fah[i], fwh[(NH) * 2 + j], acc[(MH) * 4 + i][(NH) * 2 + j], 0, 0, 0); \
        acc[(MH) * 4 + i][(NH) * 2 + j] = __builtin_amdgcn_mfma_f32_16x16x32_f16( \
            fah[i], fwl[(NH) * 2 + j], acc[(MH) * 4 + i][(NH) * 2 + j], 0, 0, 0); \
        acc[(MH) * 4 + i][(NH) * 2 + j] = __builtin_amdgcn_mfma_f32_16x16x32_f16( \
            fal[i], fwh[(NH) * 2 + j], acc[(MH) * 4 + i][(NH) * 2 + j], 0, 0, 0); \
      }                                                                      \
  } while (0)

  // prologue: ktile 0 into buf 0
  STAGE_A(0, 0);
  STAGE_W(0, 0);
  VMCNT0;
  BAR;

  for (int kt = 0; kt < NKT; ++kt) {
    const int cur = kt & 1;
    const bool pf = (kt + 1 < NKT);

    // ---- P0: A[mi0-3] + W[nj0-1] reads | A-DMAs | MM(0,0)
    DS_A(0);
    DS_W(0);
    if (pf) STAGE_A(kt + 1, cur ^ 1);
    BAR;
    LGKM0;
    PRIO1; MM(0, 0); PRIO0;
    BAR;

    // ---- P1: W[nj2-3] reads | W-DMAs | MM(0,1)
    DS_W(1);
    if (pf) STAGE_W(kt + 1, cur ^ 1);
    BAR;
    LGKM0;
    PRIO1; MM(0, 1); PRIO0;
    BAR;

    // ---- P2: A[mi4-7] reads | MM(1,0) | vmcnt(0) before end-bar
    DS_A(1);
    BAR;
    LGKM0;
    PRIO1; MM(1, 0);
    VMCNT0;                                  // kt+1's 8 DMAs, ~2.5 phases cover
    PRIO0;
    BAR;                                     // after this: buf[cur^1] ready,
                                             // buf[cur] reads all retired
    // ---- P3: MM(1,1), register-only, no barriers (overlaps next P0)
    PRIO1; MM(1, 1); PRIO0;
  }
#undef STAGE_A
#undef STAGE_W
#undef DS_A
#undef DS_W
#undef MM

  // C/D layout: col = lane&15, row = quad*4 + reg (R3/R4-verified).
  // nj innermost: consecutive stores walk consecutive 64B of one line.
  const int rowb = by * 256 + wr * 128;
  const int colb = bx * 256 + wc * 64;
#pragma unroll
  for (int mi = 0; mi < 8; ++mi)
#pragma unroll
    for (int r = 0; r < 4; ++r) {
      const size_t rowo = (size_t)(rowb + mi * 16 + quad * 4 + r) * HID;
#pragma unroll
      for (int nj = 0; nj < 4; ++nj)
        C[rowo + colb + nj * 16 + col] = acc[mi][nj][r];
    }
}

// ---------------------------------------------------------------------------
// Fused LIF scan + output projection partials (R4-verified, unchanged).
// ---------------------------------------------------------------------------
__global__ __launch_bounds__(256)
void lif_out(const float* __restrict__ cur, const float* __restrict__ wo,
             float* __restrict__ v1, float* __restrict__ i1,
             float* __restrict__ outP, int tc, int t0) {
  __shared__ _Float16 zL[T_STEPS][264];
  __shared__ _Float16 wT[16][264];

  const int tid = threadIdx.x;
  const int hc = blockIdx.x;
  const int b = blockIdx.y;
  const int hb = hc * 256;

  for (int i = tid; i < 16 * 256; i += 256) {
    const int n = i >> 8, k = i & 255;
    wT[n][k] = (n < OUT_F) ? (_Float16)wo[(size_t)n * HID + hb + k] : (_Float16)0.f;
  }

  const int sidx = b * HID + hb + tid;
  float v = v1[sidx];
  float ci = i1[sidx];
#pragma unroll 4
  for (int t = 0; t < tc; ++t) {
    const float c = cur[(size_t)t * (BATCH * HID) + sidx];
    const float vd = DEC_V * v + DT_V * ci;
    const float z = (vd > V_TH) ? 1.0f : 0.0f;
    v = (1.0f - z) * vd;
    ci = DEC_I * ci + c;
    zL[t][tid] = (_Float16)z;
  }
  v1[sidx] = v;
  i1[sidx] = ci;
  __syncthreads();

  const int wv = tid >> 6;
  const int lane = tid & 63;
  const int col = lane & 15;
  const int quad = lane >> 4;
  f32x4 acc = {};
  const _Float16* za = &zL[wv * 16 + col][0];
  const _Float16* wb = &wT[col][0];
#pragma unroll
  for (int ks = 0; ks < 8; ++ks) {
    f16x8 a = *(const f16x8*)(za + ks * 32 + quad * 8);
    f16x8 bb = *(const f16x8*)(wb + ks * 32 + quad * 8);
    acc = __builtin_amdgcn_mfma_f32_16x16x32_f16(a, bb, acc, 0, 0, 0);
  }
  if (col < OUT_F) {
#pragma unroll
    for (int r = 0; r < 4; ++r) {
      const int t = wv * 16 + quad * 4 + r;
      if (t < tc)
        outP[(((size_t)hc * T_STEPS + (t0 + t)) * BATCH + b) * OUT_F + col] = acc[r];
    }
  }
}

// ---------------------------------------------------------------------------
// LI readout: sum 8 chunk partials, scan, max. One thread per (b,o).
// ---------------------------------------------------------------------------
__global__ __launch_bounds__(256)
void li_scan(const float* __restrict__ outP, float* __restrict__ out) {
  const int idx = blockIdx.x * 256 + threadIdx.x;
  if (idx >= BATCH * OUT_F) return;
  float vo = 0.f, io = 0.f, vmax = 0.f;
  for (int t = 0; t < T_STEPS; ++t) {
    float oc = 0.f;
#pragma unroll
    for (int hc = 0; hc < 8; ++hc)
      oc += outP[((size_t)hc * T_STEPS + t) * (BATCH * OUT_F) + idx];
    const float von = DEC_V * vo + DT_V * io;
    io = DEC_I * io + oc;
    vo = von;
    vmax = fmaxf(vmax, von);
  }
  out[idx] = vmax;
}

__global__ void zero_state(float* __restrict__ p, int n) {
  int i = blockIdx.x * 256 + threadIdx.x;
  if (i < n) p[i] = 0.0f;
}

// ---------------------------------------------------------------------------
extern "C" void kernel_launch(void* const* d_in, const int* in_sizes, int n_in,
                              void* d_out, int out_size, void* d_ws, size_t ws_size,
                              hipStream_t stream) {
  const float* x  = (const float*)d_in[0];  // [T*B, 784]
  const float* w1 = (const float*)d_in[1];  // [2048, 784]
  const float* wo = (const float*)d_in[2];  // [10, 2048]
  float* out = (float*)d_out;               // [512, 10]

  const size_t BH = (size_t)BATCH * HID;
  const size_t WT_HALVES = (size_t)(HID / 16) * NKT * 512;   // per W array

  // fixed: v1 | i1 | outP[8][T*B*10] | WhT | WlT ; chunk: cur | AhT | AlT
  float* v1 = (float*)d_ws;
  float* i1 = v1 + BH;
  float* outP = i1 + BH;
  _Float16* WhT = (_Float16*)(outP + (size_t)8 * T_STEPS * BATCH * OUT_F);
  _Float16* WlT = WhT + WT_HALVES;
  char* chunk0 = (char*)(WlT + WT_HALVES);

  const size_t base_bytes = (size_t)(chunk0 - (char*)d_ws);
  // per step: cur f32 [512,2048] + AhT/AlT f16 [32 tiles][25][512]
  const size_t per_step = BH * 4 + (size_t)2 * 32 * NKT * 512 * 2;
  int Tc = T_STEPS;
  while (Tc > 1 && base_bytes + (size_t)Tc * per_step > ws_size) Tc >>= 1;

  float* cur = (float*)chunk0;
  _Float16* AhT = (_Float16*)(cur + (size_t)Tc * BH);
  _Float16* AlT = AhT + (size_t)Tc * 32 * NKT * 512;

  split_frag<<<HID / 16, 256, 0, stream>>>(w1, WhT, WlT);
  zero_state<<<(int)((2 * BH + 255) / 256), 256, 0, stream>>>(v1, (int)(2 * BH));

  for (int t0 = 0; t0 < T_STEPS; t0 += Tc) {
    const int tc = (T_STEPS - t0 < Tc) ? (T_STEPS - t0) : Tc;
    const int nrows = tc * BATCH;
    split_frag<<<nrows / 16, 256, 0, stream>>>(x + (size_t)t0 * BATCH * IN_F, AhT, AlT);
    dim3 grid(HID / 256, nrows / 256);       // 256x256 block tile, 512 thr
    gemm_fc1<<<grid, 512, 0, stream>>>(AhT, AlT, WhT, WlT, cur);
    dim3 lgrid(HID / 256, BATCH);
    lif_out<<<lgrid, 256, 0, stream>>>(cur, wo, v1, i1, outP, tc, t0);
  }
  li_scan<<<(BATCH * OUT_F + 255) / 256, 256, 0, stream>>>(outP, out);
}